// Round 7
// baseline (135.763 us; speedup 1.0000x reference)
//
#include <hip/hip_runtime.h>
#include <hip/hip_bf16.h>

#define ATTN_N 8192
#define ATTN_D 128
#define TKEYS 128                     // keys per LDS tile
#define NTILES (ATTN_N / TKEYS)       // 64
#define TILE_ELEMS (TKEYS * ATTN_D)   // 16384 bf16 = 32 KB
#define QROWS 128                     // queries per block
#define NSPLIT 4                      // split-K ways
#define KTPB (NTILES / NSPLIT)        // 16 key tiles per block

typedef __bf16 bf16_t;
typedef bf16_t bf16x2 __attribute__((ext_vector_type(2)));
typedef bf16_t bf16x8 __attribute__((ext_vector_type(8)));
typedef float f32x4 __attribute__((ext_vector_type(4)));

#if __has_builtin(__builtin_amdgcn_exp2f)
#define EXP2(x) __builtin_amdgcn_exp2f(x)
#else
#define EXP2(x) __expf((x) * 0.6931471805599453f)
#endif

// Async global->LDS DMA, 16 B per lane; lane-linear on both sides (m104).
__device__ __forceinline__ void dma16(const bf16_t* g, bf16_t* l) {
  __builtin_amdgcn_global_load_lds(
      (const __attribute__((address_space(1))) void*)g,
      (__attribute__((address_space(3))) void*)l, 16, 0, 0);
}

// ---------------------------------------------------------------------------
// Prep (unchanged from R6): Q -> bf16 linear (scaled log2(e)/sqrt(128));
// K -> swizzled tile image; V -> transposed interleaved swizzled tile image.
// ---------------------------------------------------------------------------
__global__ void prep_kernel(const float* __restrict__ q,
                            const float* __restrict__ k,
                            const float* __restrict__ v,
                            bf16_t* __restrict__ qb,
                            bf16_t* __restrict__ kswz,
                            bf16_t* __restrict__ vtswz) {
  __shared__ bf16_t tile[64][72];
  const int bk = blockIdx.x;      // 64-key block, 0..127
  const int bd = blockIdx.y;      // 64-d half, 0..1
  const int t = threadIdx.x;      // 0..255
  const float sc = 0.12751744f;   // log2(e) / sqrt(128)

  const int row_l = t >> 2;             // 0..63
  const int key = bk * 64 + row_l;
  const int kt = key >> 7;
  const int r = key & 127;

#pragma unroll
  for (int u = 0; u < 2; ++u) {
    const int j = bd * 8 + (t & 3) * 2 + u;   // d-chunk 0..15
    const float4* qs = (const float4*)(q + (size_t)key * ATTN_D + j * 8);
    const float4* ks = (const float4*)(k + (size_t)key * ATTN_D + j * 8);
    float4 a0 = qs[0], a1 = qs[1];
    float4 b0 = ks[0], b1 = ks[1];
    bf16x8 qo, ko;
    qo[0] = (bf16_t)(a0.x * sc); qo[1] = (bf16_t)(a0.y * sc);
    qo[2] = (bf16_t)(a0.z * sc); qo[3] = (bf16_t)(a0.w * sc);
    qo[4] = (bf16_t)(a1.x * sc); qo[5] = (bf16_t)(a1.y * sc);
    qo[6] = (bf16_t)(a1.z * sc); qo[7] = (bf16_t)(a1.w * sc);
    ko[0] = (bf16_t)b0.x; ko[1] = (bf16_t)b0.y;
    ko[2] = (bf16_t)b0.z; ko[3] = (bf16_t)b0.w;
    ko[4] = (bf16_t)b1.x; ko[5] = (bf16_t)b1.y;
    ko[6] = (bf16_t)b1.z; ko[7] = (bf16_t)b1.w;
    *(bf16x8*)(qb + (size_t)key * ATTN_D + j * 8) = qo;
    *(bf16x8*)(kswz + (size_t)kt * TILE_ELEMS + r * ATTN_D + (j ^ (r & 15)) * 8) = ko;
  }

  {
    const float* src = v + (size_t)key * ATTN_D + bd * 64 + (t & 3) * 16;
#pragma unroll
    for (int u = 0; u < 4; ++u) {
      float4 a = ((const float4*)src)[u];
      tile[row_l][(t & 3) * 16 + u * 4 + 0] = (bf16_t)a.x;
      tile[row_l][(t & 3) * 16 + u * 4 + 1] = (bf16_t)a.y;
      tile[row_l][(t & 3) * 16 + u * 4 + 2] = (bf16_t)a.z;
      tile[row_l][(t & 3) * 16 + u * 4 + 3] = (bf16_t)a.w;
    }
  }
  __syncthreads();
  {
    const int d_l = t >> 2;            // 0..63
    const int d = bd * 64 + d_l;
    const int h = bk & 1;              // which half of the 128-key tile
    const int ktv = bk >> 1;
#pragma unroll
    for (int u = 0; u < 2; ++u) {
      const int j = 8 * h + (t & 3) * 2 + u;   // key-chunk position 0..15
      bf16x8 o;
#pragma unroll
      for (int i = 0; i < 8; ++i) {
        const int key_tile = (j >> 2) * 32 + 4 * (j & 3) + (i >> 1) + 16 * (i & 1);
        o[i] = tile[key_tile - h * 64][d_l];
      }
      *(bf16x8*)(vtswz + (size_t)ktv * TILE_ELEMS + d * TKEYS + (j ^ (d & 15)) * 8) = o;
    }
  }
}

// ---------------------------------------------------------------------------
// Flash attention, 128 queries/block x 4-way split-K.
//   grid = 256 blocks (qg = blk>>2, kh = blk&3) x 512 threads (8 waves).
//   kh is constant per XCD (blk%8 = XCD) -> each XCD L2 holds only its
//   1 MB K-quarter + 1 MB V-quarter.
//   Wave (rowG = w&1, keyQ = w>>1): 64 rows x 32-key window per tile,
//   as 4 m-subtiles (mi) of 16 rows. Each K-frag LDS read feeds 4 MFMAs,
//   each V-frag read feeds 2 (m-subtiles processed in 2 softmax/PV groups
//   so the per-wave Ps buffer stays at 32 rows).
//   exp2-only softmax (pure-sum denominator), DMA double-buffer, one
//   barrier/iter. Writes unnormalized partial O + partial L; merge kernel
//   does the linear 4-way combine + normalize.
// MFMA layouts (mfma_f32_16x16x32_bf16, verified gfx950):
//   A: m = lane&15, k = (lane>>4)*8 + j
//   B: n = lane&15, k = (lane>>4)*8 + j
//   C/D: col = lane&15, row = (lane>>4)*4 + reg
// ---------------------------------------------------------------------------
__global__ __launch_bounds__(512) void flash_attn_kernel(
    const bf16_t* __restrict__ qb, const bf16_t* __restrict__ kswz,
    const bf16_t* __restrict__ vtswz, float* __restrict__ partO,
    float* __restrict__ partL) {
  __shared__ __align__(16) bf16_t KV[2][2][TILE_ELEMS];  // 128 KB
  __shared__ __align__(16) bf16_t Ps[8][32][40];         // 20 KB
  __shared__ float cmb[8][64];                           // 2 KB
  // Epilogue-only merge buffer aliased over the (dead) KV storage.
  float* Ob = (float*)&KV[0][0][0];                      // [128][132]

  const int t = threadIdx.x;
  const int w = t >> 6;
  const int lane = t & 63;
  const int quad = lane >> 4;
  const int col = lane & 15;
  const int rowG = w & 1;          // 64-row group
  const int keyQ = w >> 1;         // 32-key window
  const int blk = blockIdx.x;
  const int qg = blk >> 2;
  const int kh = blk & 3;
  const int q0 = qg * QROWS;
  const int ktbase = kh * KTPB;
  const int stg = ((blk >> 3) & 3) * 4;   // intra-XCD phase decorrelation

  // Swizzled LDS offsets (row*128 + (chunk^col)*8; row&15==col cancels).
  int offK[4][2], offV[8];
#pragma unroll
  for (int c = 0; c < 4; ++c)
#pragma unroll
    for (int cs = 0; cs < 2; ++cs)
      offK[c][cs] = (keyQ * 32 + cs * 16 + col) * ATTN_D +
                    (((c * 4 + quad) ^ col) * 8);
#pragma unroll
  for (int ds = 0; ds < 8; ++ds)
    offV[ds] = (ds * 16 + col) * TKEYS + (((keyQ * 4 + quad) ^ col) * 8);

  // Q fragments: 4 m-subtiles x 4 k-chunks, registers for whole kernel.
  bf16x8 aq[4][4];
#pragma unroll
  for (int mi = 0; mi < 4; ++mi) {
    const int row = q0 + rowG * 64 + mi * 16 + col;
#pragma unroll
    for (int c = 0; c < 4; ++c)
      aq[mi][c] = *(const bf16x8*)(qb + (size_t)row * ATTN_D + c * 32 + quad * 8);
  }

  f32x4 oacc[4][8];
#pragma unroll
  for (int mi = 0; mi < 4; ++mi)
#pragma unroll
    for (int i = 0; i < 8; ++i) oacc[mi][i] = (f32x4){0.f, 0.f, 0.f, 0.f};
  float l_part[4][4];
#pragma unroll
  for (int mi = 0; mi < 4; ++mi)
#pragma unroll
    for (int r = 0; r < 4; ++r) l_part[mi][r] = 0.f;

  // Prologue DMA: first tile into buf 0.
  {
    const int kt = ktbase + (stg & (KTPB - 1));
    const bf16_t* kg = kswz + (size_t)kt * TILE_ELEMS + t * 8;
    const bf16_t* vg = vtswz + (size_t)kt * TILE_ELEMS + t * 8;
#pragma unroll
    for (int u = 0; u < 4; ++u) {
      dma16(kg + u * 4096, &KV[0][0][t * 8 + u * 4096]);
      dma16(vg + u * 4096, &KV[0][1][t * 8 + u * 4096]);
    }
  }
  __syncthreads();

  for (int it = 0; it < KTPB; ++it) {
    const int buf = it & 1;
    if (it + 1 < KTPB) {
      const int nt = ktbase + ((stg + it + 1) & (KTPB - 1));
      const bf16_t* kg = kswz + (size_t)nt * TILE_ELEMS + t * 8;
      const bf16_t* vg = vtswz + (size_t)nt * TILE_ELEMS + t * 8;
      bf16_t* kl = &KV[buf ^ 1][0][t * 8];
      bf16_t* vl = &KV[buf ^ 1][1][t * 8];
#pragma unroll
      for (int u = 0; u < 4; ++u) {
        dma16(kg + u * 4096, kl + u * 4096);
        dma16(vg + u * 4096, vl + u * 4096);
      }
    }
    const bf16_t* Kb = KV[buf][0];
    const bf16_t* Vb = KV[buf][1];

    // --- S = Q K^T: 4 m-subtiles x 2 n-subtiles; each K frag feeds 4 MFMAs.
    f32x4 s[4][2];
#pragma unroll
    for (int mi = 0; mi < 4; ++mi)
#pragma unroll
      for (int ni = 0; ni < 2; ++ni) s[mi][ni] = (f32x4){0.f, 0.f, 0.f, 0.f};
#pragma unroll
    for (int c = 0; c < 4; ++c) {
      bf16x8 b0 = *(const bf16x8*)(Kb + offK[c][0]);
      bf16x8 b1 = *(const bf16x8*)(Kb + offK[c][1]);
#pragma unroll
      for (int mi = 0; mi < 4; ++mi)
        s[mi][0] = __builtin_amdgcn_mfma_f32_16x16x32_bf16(aq[mi][c], b0, s[mi][0], 0, 0, 0);
#pragma unroll
      for (int mi = 0; mi < 4; ++mi)
        s[mi][1] = __builtin_amdgcn_mfma_f32_16x16x32_bf16(aq[mi][c], b1, s[mi][1], 0, 0, 0);
    }

    // --- softmax + PV in 2 groups of 2 m-subtiles (Ps buffer reuse; LDS
    //     write->read same wave needs only lgkmcnt, no barrier).
#pragma unroll
    for (int g = 0; g < 2; ++g) {
#pragma unroll
      for (int mj = 0; mj < 2; ++mj) {
        const int mi = 2 * g + mj;
#pragma unroll
        for (int r = 0; r < 4; ++r) {
          float p0 = EXP2(s[mi][0][r]);
          float p1 = EXP2(s[mi][1][r]);
          l_part[mi][r] += p0 + p1;
          *(bf16x2*)&Ps[w][mj * 16 + quad * 4 + r][col * 2] =
              (bf16x2){(bf16_t)p0, (bf16_t)p1};
        }
      }
      bf16x8 ap0 = *(const bf16x8*)&Ps[w][col][quad * 8];
      bf16x8 ap1 = *(const bf16x8*)&Ps[w][16 + col][quad * 8];
#pragma unroll
      for (int ds = 0; ds < 8; ++ds) {
        bf16x8 bv = *(const bf16x8*)(Vb + offV[ds]);
        oacc[2 * g][ds] =
            __builtin_amdgcn_mfma_f32_16x16x32_bf16(ap0, bv, oacc[2 * g][ds], 0, 0, 0);
        oacc[2 * g + 1][ds] =
            __builtin_amdgcn_mfma_f32_16x16x32_bf16(ap1, bv, oacc[2 * g + 1][ds], 0, 0, 0);
      }
    }
    __syncthreads();  // drains prefetch vmcnt + protects buffer swap
  }

  // --- epilogue: denominator reduce -> partL.
#pragma unroll
  for (int mi = 0; mi < 4; ++mi)
#pragma unroll
    for (int r = 0; r < 4; ++r) {
      float v = l_part[mi][r];
#pragma unroll
      for (int off = 1; off < 16; off <<= 1)
        v += __shfl_xor(v, off, 64);
      if (col == 0) cmb[w][mi * 16 + quad * 4 + r] = v;
    }
  __syncthreads();
  if (t < QROWS) {
    const int rg = t >> 6, rl = t & 63;
    partL[(size_t)blk * QROWS + t] = cmb[rg][rl] + cmb[rg + 2][rl] +
                                     cmb[rg + 4][rl] + cmb[rg + 6][rl];
  }

  // --- 4-way keyQ merge of O into Ob (aliased on KV; stride 132).
#pragma unroll
  for (int p = 0; p < 4; ++p) {
    if (keyQ == p) {
#pragma unroll
      for (int mi = 0; mi < 4; ++mi)
#pragma unroll
        for (int ds = 0; ds < 8; ++ds)
#pragma unroll
          for (int r = 0; r < 4; ++r) {
            const int row = rowG * 64 + mi * 16 + quad * 4 + r;
            if (p == 0)
              Ob[row * 132 + ds * 16 + col] = oacc[mi][ds][r];
            else
              Ob[row * 132 + ds * 16 + col] += oacc[mi][ds][r];
          }
    }
    __syncthreads();
  }

  // --- cooperative write of the unnormalized 128x128 partial O.
  {
    float* dst = partO + (size_t)blk * (QROWS * ATTN_D);
    const int row = t >> 2;
    const int c0 = (t & 3) * 32;
#pragma unroll
    for (int u = 0; u < 8; ++u) {
      float4 vv = *(float4*)&Ob[row * 132 + c0 + u * 4];
      *(float4*)(dst + row * ATTN_D + c0 + u * 4) = vv;
    }
  }
}

// ---------------------------------------------------------------------------
// Merge: out[row] = sum_j O_j[row] / sum_j L_j[row], j = 4 split-K parts.
//   1024 blocks x 256 threads, one float4 per thread.
// ---------------------------------------------------------------------------
__global__ void merge_kernel(const float* __restrict__ partO,
                             const float* __restrict__ partL,
                             float* __restrict__ out) {
  const int idx = blockIdx.x * blockDim.x + threadIdx.x;  // float4 index
  const int row = idx >> 5;          // 32 float4 per 128-elem row
  const int gi = row >> 7;           // query group
  const int rl = row & 127;
  const int li = rl * 32 + (idx & 31);
  float L = 0.f;
  float4 o = {0.f, 0.f, 0.f, 0.f};
#pragma unroll
  for (int j = 0; j < NSPLIT; ++j) {
    const int blk = gi * NSPLIT + j;
    const float4 a =
        ((const float4*)(partO + (size_t)blk * (QROWS * ATTN_D)))[li];
    L += partL[(size_t)blk * QROWS + rl];
    o.x += a.x; o.y += a.y; o.z += a.z; o.w += a.w;
  }
  const float invL = 1.0f / L;
  o.x *= invL; o.y *= invL; o.z *= invL; o.w *= invL;
  ((float4*)out)[idx] = o;
}

// ---------------------------------------------------------------------------
extern "C" void kernel_launch(void* const* d_in, const int* in_sizes, int n_in,
                              void* d_out, int out_size, void* d_ws, size_t ws_size,
                              hipStream_t stream) {
  const float* q = (const float*)d_in[0];
  const float* k = (const float*)d_in[1];
  const float* v = (const float*)d_in[2];
  float* out = (float*)d_out;

  // Workspace: qb|kswz|vtswz (bf16, 2 MB each) | partO 16 MB | partL 128 KB.
  bf16_t* qb = (bf16_t*)d_ws;
  bf16_t* kswz = qb + (size_t)ATTN_N * ATTN_D;
  bf16_t* vtswz = kswz + (size_t)ATTN_N * ATTN_D;
  float* partO = (float*)(vtswz + (size_t)ATTN_N * ATTN_D);
  float* partL = partO + (size_t)256 * QROWS * ATTN_D;

  prep_kernel<<<dim3(ATTN_N / 64, 2), 256, 0, stream>>>(q, k, v, qb, kswz, vtswz);
  flash_attn_kernel<<<256, 512, 0, stream>>>(qb, kswz, vtswz, partO, partL);
  merge_kernel<<<(ATTN_N * ATTN_D / 4) / 256, 256, 0, stream>>>(partO, partL, out);
}

// Round 9
// 132.034 us; speedup vs baseline: 1.0282x; 1.0282x over previous
//
#include <hip/hip_runtime.h>
#include <hip/hip_bf16.h>

#define ATTN_N 8192
#define ATTN_D 128
#define TKEYS 64                      // keys per LDS tile
#define NTILES (ATTN_N / TKEYS)       // 128
#define TILE_ELEMS (TKEYS * ATTN_D)   // 8192 bf16 = 16 KB
#define QROWS 64                      // queries per block
#define NSPLIT 4                      // split-K ways
#define KTPB (NTILES / NSPLIT)        // 32 key tiles per block

typedef __bf16 bf16_t;
typedef bf16_t bf16x2 __attribute__((ext_vector_type(2)));
typedef bf16_t bf16x8 __attribute__((ext_vector_type(8)));
typedef float f32x4 __attribute__((ext_vector_type(4)));

#if __has_builtin(__builtin_amdgcn_exp2f)
#define EXP2(x) __builtin_amdgcn_exp2f(x)
#else
#define EXP2(x) __expf((x) * 0.6931471805599453f)
#endif

// Async global->LDS DMA, 16 B per lane; lane-linear on both sides (m104).
__device__ __forceinline__ void dma16(const bf16_t* g, bf16_t* l) {
  __builtin_amdgcn_global_load_lds(
      (const __attribute__((address_space(1))) void*)g,
      (__attribute__((address_space(3))) void*)l, 16, 0, 0);
}

// ---------------------------------------------------------------------------
// Prep: Q -> bf16 linear (scaled by log2(e)/sqrt(128), flash uses exp2);
//       K -> 64-key tile image kswz: tile kt = key>>6, row r = key&63,
//            16B d-chunk j stored at j ^ (r&15);
//       V -> transposed 64-key tile image vtswz: tile kt, row d (0..127),
//            64 key-positions pairwise interleaved per 32-key window
//            (local pos 2i <-> key i, 2i+1 <-> key i+16), 8 chunks XOR (d&7).
//   grid (N/64, 2) x 256 threads; block bk covers exactly one 64-key tile.
// ---------------------------------------------------------------------------
__global__ void prep_kernel(const float* __restrict__ q,
                            const float* __restrict__ k,
                            const float* __restrict__ v,
                            bf16_t* __restrict__ qb,
                            bf16_t* __restrict__ kswz,
                            bf16_t* __restrict__ vtswz) {
  __shared__ bf16_t tile[64][72];
  const int bk = blockIdx.x;      // 64-key tile index, 0..127
  const int bd = blockIdx.y;      // 64-d half, 0..1
  const int t = threadIdx.x;      // 0..255
  const float sc = 0.12751744f;   // log2(e) / sqrt(128)

  const int row_l = t >> 2;             // 0..63 (key within tile)
  const int key = bk * 64 + row_l;

  // --- Q (linear) + K (chunk-swizzled): 2 chunks of 8 elems per thread.
#pragma unroll
  for (int u = 0; u < 2; ++u) {
    const int j = bd * 8 + (t & 3) * 2 + u;   // d-chunk 0..15
    const float4* qs = (const float4*)(q + (size_t)key * ATTN_D + j * 8);
    const float4* ks = (const float4*)(k + (size_t)key * ATTN_D + j * 8);
    float4 a0 = qs[0], a1 = qs[1];
    float4 b0 = ks[0], b1 = ks[1];
    bf16x8 qo, ko;
    qo[0] = (bf16_t)(a0.x * sc); qo[1] = (bf16_t)(a0.y * sc);
    qo[2] = (bf16_t)(a0.z * sc); qo[3] = (bf16_t)(a0.w * sc);
    qo[4] = (bf16_t)(a1.x * sc); qo[5] = (bf16_t)(a1.y * sc);
    qo[6] = (bf16_t)(a1.z * sc); qo[7] = (bf16_t)(a1.w * sc);
    ko[0] = (bf16_t)b0.x; ko[1] = (bf16_t)b0.y;
    ko[2] = (bf16_t)b0.z; ko[3] = (bf16_t)b0.w;
    ko[4] = (bf16_t)b1.x; ko[5] = (bf16_t)b1.y;
    ko[6] = (bf16_t)b1.z; ko[7] = (bf16_t)b1.w;
    *(bf16x8*)(qb + (size_t)key * ATTN_D + j * 8) = qo;
    *(bf16x8*)(kswz + (size_t)bk * TILE_ELEMS + row_l * ATTN_D +
               (j ^ (row_l & 15)) * 8) = ko;
  }

  // --- V: stage 64 keys x 64 d (this bd half) as bf16, then write out
  //     transposed + interleaved + swizzled.
  {
    const float* src = v + (size_t)key * ATTN_D + bd * 64 + (t & 3) * 16;
#pragma unroll
    for (int u = 0; u < 4; ++u) {
      float4 a = ((const float4*)src)[u];
      tile[row_l][(t & 3) * 16 + u * 4 + 0] = (bf16_t)a.x;
      tile[row_l][(t & 3) * 16 + u * 4 + 1] = (bf16_t)a.y;
      tile[row_l][(t & 3) * 16 + u * 4 + 2] = (bf16_t)a.z;
      tile[row_l][(t & 3) * 16 + u * 4 + 3] = (bf16_t)a.w;
    }
  }
  __syncthreads();
  {
    const int d_l = t >> 2;            // 0..63
    const int d = bd * 64 + d_l;       // V-tile row
#pragma unroll
    for (int u = 0; u < 2; ++u) {
      const int j = (t & 3) * 2 + u;   // key-chunk position 0..7
      bf16x8 o;
#pragma unroll
      for (int i = 0; i < 8; ++i) {
        const int p = 8 * j + i;       // global position 0..63
        const int lp = p & 31;
        const int key_t = (p >> 5) * 32 + (lp >> 1) + 16 * (lp & 1);
        o[i] = tile[key_t][d_l];
      }
      *(bf16x8*)(vtswz + (size_t)bk * TILE_ELEMS + d * TKEYS +
                 ((j ^ (d & 7)) * 8)) = o;
    }
  }
}

// ---------------------------------------------------------------------------
// Flash attention, 64 queries/block x 4-way split-K, 2 blocks/CU.
//   grid = 512 blocks (qg = blk>>2, kh = blk&3) x 512 threads (8 waves).
//   kh is constant per XCD (blk%8 = XCD) -> each XCD L2 holds only its
//   0.5 MB K-quarter + 0.5 MB V-quarter.
//   Wave (rowG = w&3, keyH = w>>2): 16 rows x 32-key window of the 64-key
//   tile. LDS ~75 KB -> 2 blocks/CU -> 16 waves/CU (4/SIMD): short serial
//   chains + double the latency-hiding TLP vs R6/R7.
//   exp2-only softmax (pure-sum denominator), DMA double-buffer, one
//   barrier/iter. Unnormalized partial O + partial L out (nontemporal, to
//   keep K/V resident in L2); merge kernel does linear combine + normalize.
// MFMA layouts (mfma_f32_16x16x32_bf16, verified gfx950):
//   A: m = lane&15, k = (lane>>4)*8 + j
//   B: n = lane&15, k = (lane>>4)*8 + j
//   C/D: col = lane&15, row = (lane>>4)*4 + reg
// ---------------------------------------------------------------------------
__global__ __launch_bounds__(512, 4) void flash_attn_kernel(
    const bf16_t* __restrict__ qb, const bf16_t* __restrict__ kswz,
    const bf16_t* __restrict__ vtswz, float* __restrict__ partO,
    float* __restrict__ partL) {
  __shared__ __align__(16) bf16_t KV[2][2][TILE_ELEMS];  // 64 KB
  __shared__ __align__(16) bf16_t Ps[8][16][40];         // 10 KB
  __shared__ float cmb[8][16];                           // 0.5 KB
  // Epilogue-only merge buffer aliased over the (dead) KV storage.
  float* Ob = (float*)&KV[0][0][0];                      // [64][132] = 33.8 KB

  const int t = threadIdx.x;
  const int w = t >> 6;
  const int lane = t & 63;
  const int quad = lane >> 4;
  const int col = lane & 15;
  const int rowG = w & 3;          // 16-row group
  const int keyH = w >> 2;         // 32-key window
  const int blk = blockIdx.x;
  const int qg = blk >> 2;
  const int kh = blk & 3;
  const int q0 = qg * QROWS;
  const int ktbase = kh * KTPB;
  const int stg = ((blk >> 3) & 7) * 4;   // intra-XCD phase decorrelation

  // Swizzled LDS element offsets for fragment reads.
  // K row r = keyH*32+cs*16+col has r&15 == col -> stored chunk (c*4+quad)^col.
  int offK[4][2], offV[8];
#pragma unroll
  for (int c = 0; c < 4; ++c)
#pragma unroll
    for (int cs = 0; cs < 2; ++cs)
      offK[c][cs] = (keyH * 32 + cs * 16 + col) * ATTN_D +
                    (((c * 4 + quad) ^ col) * 8);
  // V row d = ds*16+col has d&7 == col&7 -> chunk (keyH*4+quad)^(col&7).
#pragma unroll
  for (int ds = 0; ds < 8; ++ds)
    offV[ds] = (ds * 16 + col) * TKEYS + (((keyH * 4 + quad) ^ (col & 7)) * 8);

  // Q fragments: 16 rows, 4 k-chunks, registers for the whole kernel.
  bf16x8 aq[4];
  {
    const int row = q0 + rowG * 16 + col;
#pragma unroll
    for (int c = 0; c < 4; ++c)
      aq[c] = *(const bf16x8*)(qb + (size_t)row * ATTN_D + c * 32 + quad * 8);
  }

  f32x4 oacc[8];
#pragma unroll
  for (int i = 0; i < 8; ++i) oacc[i] = (f32x4){0.f, 0.f, 0.f, 0.f};
  float l_part[4] = {0.f, 0.f, 0.f, 0.f};

  // Prologue DMA: first tile into buf 0 (512 thr x 2 chunks per operand).
  {
    const int kt = ktbase + (stg & (KTPB - 1));
    const bf16_t* kg = kswz + (size_t)kt * TILE_ELEMS + t * 8;
    const bf16_t* vg = vtswz + (size_t)kt * TILE_ELEMS + t * 8;
#pragma unroll
    for (int u = 0; u < 2; ++u) {
      dma16(kg + u * 4096, &KV[0][0][t * 8 + u * 4096]);
      dma16(vg + u * 4096, &KV[0][1][t * 8 + u * 4096]);
    }
  }
  __syncthreads();

  for (int it = 0; it < KTPB; ++it) {
    const int buf = it & 1;
    if (it + 1 < KTPB) {
      const int nt = ktbase + ((stg + it + 1) & (KTPB - 1));
      const bf16_t* kg = kswz + (size_t)nt * TILE_ELEMS + t * 8;
      const bf16_t* vg = vtswz + (size_t)nt * TILE_ELEMS + t * 8;
      bf16_t* kl = &KV[buf ^ 1][0][t * 8];
      bf16_t* vl = &KV[buf ^ 1][1][t * 8];
#pragma unroll
      for (int u = 0; u < 2; ++u) {
        dma16(kg + u * 4096, kl + u * 4096);
        dma16(vg + u * 4096, vl + u * 4096);
      }
    }
    const bf16_t* Kb = KV[buf][0];
    const bf16_t* Vb = KV[buf][1];

    // --- S = Q K^T over this wave's 32-key window (2 n-subtiles).
    f32x4 s0 = (f32x4){0.f, 0.f, 0.f, 0.f};
    f32x4 s1 = (f32x4){0.f, 0.f, 0.f, 0.f};
#pragma unroll
    for (int c = 0; c < 4; ++c) {
      bf16x8 b0 = *(const bf16x8*)(Kb + offK[c][0]);
      s0 = __builtin_amdgcn_mfma_f32_16x16x32_bf16(aq[c], b0, s0, 0, 0, 0);
      bf16x8 b1 = *(const bf16x8*)(Kb + offK[c][1]);
      s1 = __builtin_amdgcn_mfma_f32_16x16x32_bf16(aq[c], b1, s1, 0, 0, 0);
    }

    // --- p = 2^s; lane-local denominator; packed pair-store (local key
    //     col <-> pos 2*col, key col+16 <-> pos 2*col+1).
#pragma unroll
    for (int r = 0; r < 4; ++r) {
      float p0 = EXP2(s0[r]);
      float p1 = EXP2(s1[r]);
      l_part[r] += p0 + p1;
      *(bf16x2*)&Ps[w][quad * 4 + r][col * 2] = (bf16x2){(bf16_t)p0, (bf16_t)p1};
    }

    // --- O += P V.
    bf16x8 ap = *(const bf16x8*)&Ps[w][col][quad * 8];
#pragma unroll
    for (int ds = 0; ds < 8; ++ds) {
      bf16x8 bv = *(const bf16x8*)(Vb + offV[ds]);
      oacc[ds] = __builtin_amdgcn_mfma_f32_16x16x32_bf16(ap, bv, oacc[ds], 0, 0, 0);
    }
    __syncthreads();  // drains prefetch vmcnt + protects buffer swap
  }

  // --- epilogue: denominator reduce -> partL (row t: waves rowG=t>>4).
#pragma unroll
  for (int r = 0; r < 4; ++r) {
    float v = l_part[r];
#pragma unroll
    for (int off = 1; off < 16; off <<= 1)
      v += __shfl_xor(v, off, 64);
    if (col == 0) cmb[w][quad * 4 + r] = v;
  }
  __syncthreads();
  if (t < QROWS) {
    partL[(size_t)blk * QROWS + t] = cmb[t >> 4][t & 15] + cmb[(t >> 4) + 4][t & 15];
  }

  // --- 2-way keyH merge of O into Ob (aliased on dead KV; stride 132).
  if (keyH == 0) {
#pragma unroll
    for (int ds = 0; ds < 8; ++ds)
#pragma unroll
      for (int r = 0; r < 4; ++r) {
        const int row = rowG * 16 + quad * 4 + r;
        Ob[row * 132 + ds * 16 + col] = oacc[ds][r];
      }
  }
  __syncthreads();
  if (keyH == 1) {
#pragma unroll
    for (int ds = 0; ds < 8; ++ds)
#pragma unroll
      for (int r = 0; r < 4; ++r) {
        const int row = rowG * 16 + quad * 4 + r;
        Ob[row * 132 + ds * 16 + col] += oacc[ds][r];
      }
  }
  __syncthreads();

  // --- cooperative nontemporal write of the unnormalized 64x128 partial O.
  {
    float* dst = partO + (size_t)blk * (QROWS * ATTN_D);
    const int row = t >> 3;
    const int c0 = (t & 7) * 16;
#pragma unroll
    for (int u = 0; u < 4; ++u) {
      f32x4 vv = *(f32x4*)&Ob[row * 132 + c0 + u * 4];
      __builtin_nontemporal_store(vv, (f32x4*)(dst + row * ATTN_D + c0 + u * 4));
    }
  }
}

// ---------------------------------------------------------------------------
// Merge: out[row] = sum_j O_j[row] / sum_j L_j[row], j = 4 split-K parts.
//   1024 blocks x 256 threads, one float4 per thread; nontemporal reads.
// ---------------------------------------------------------------------------
__global__ void merge_kernel(const float* __restrict__ partO,
                             const float* __restrict__ partL,
                             float* __restrict__ out) {
  const int idx = blockIdx.x * blockDim.x + threadIdx.x;  // float4 index
  const int row = idx >> 5;          // 32 float4 per 128-elem row
  const int gi = row >> 6;           // query group
  const int rl = row & 63;
  const int li = rl * 32 + (idx & 31);
  float L = 0.f;
  f32x4 o = (f32x4){0.f, 0.f, 0.f, 0.f};
#pragma unroll
  for (int j = 0; j < NSPLIT; ++j) {
    const int blk = gi * NSPLIT + j;
    const f32x4 a = __builtin_nontemporal_load(
        (const f32x4*)(partO + (size_t)blk * (QROWS * ATTN_D)) + li);
    L += partL[(size_t)blk * QROWS + rl];
    o += a;
  }
  const float invL = 1.0f / L;
  o *= invL;
  *((f32x4*)out + idx) = o;
}

// ---------------------------------------------------------------------------
extern "C" void kernel_launch(void* const* d_in, const int* in_sizes, int n_in,
                              void* d_out, int out_size, void* d_ws, size_t ws_size,
                              hipStream_t stream) {
  const float* q = (const float*)d_in[0];
  const float* k = (const float*)d_in[1];
  const float* v = (const float*)d_in[2];
  float* out = (float*)d_out;

  // Workspace: qb|kswz|vtswz (bf16, 2 MB each) | partO 16 MB | partL 128 KB.
  bf16_t* qb = (bf16_t*)d_ws;
  bf16_t* kswz = qb + (size_t)ATTN_N * ATTN_D;
  bf16_t* vtswz = kswz + (size_t)ATTN_N * ATTN_D;
  float* partO = (float*)(vtswz + (size_t)ATTN_N * ATTN_D);
  float* partL = partO + (size_t)512 * QROWS * ATTN_D;

  prep_kernel<<<dim3(ATTN_N / 64, 2), 256, 0, stream>>>(q, k, v, qb, kswz, vtswz);
  flash_attn_kernel<<<512, 512, 0, stream>>>(qb, kswz, vtswz, partO, partL);
  merge_kernel<<<(ATTN_N * ATTN_D / 4) / 256, 256, 0, stream>>>(partO, partL, out);
}